// Round 4
// baseline (9653.533 us; speedup 1.0000x reference)
//
#include <hip/hip_runtime.h>
#include <stdint.h>

#define NTOT    131072
#define NSTEP   60
#define SBLK    32             // samples per block: 4 waves, 1 wave/SIMD quantum
#define NBLK    (NTOT / SBLK)  // 4096 blocks
#define PLANE_H 16384          // halves per A-image plane (128x128 frag order)
#define IMG_H   32768          // halves per A image (hi + lo plane)
#define BPLANE_H 4096          // halves per ACT plane (128k x 32n frag order)
#define ACT_H   8192           // halves per ACT image (hi + lo)

// LDS: double-buffered ACT (2 x 16 KB) kills the gemm<->epilogue barrier.
// 38.1 KB/block -> up to 4 blocks/CU if regs allow.
#define OFF_ACT0 0             // 16384 B
#define OFF_ACT1 16384         // 16384 B
#define OFF_GP   32768         // 4*32*2*4 = 1024 B
#define OFF_W1C  33792         // 2048 B
#define OFF_B2   35840         // 512 B
#define OFF_B3   36352
#define OFF_B4   36864
#define OFF_W5   37376
#define OFF_XB   37888         // 32*2*4 = 256 B
#define LDS_TOTAL 38144

typedef float  f32x4  __attribute__((ext_vector_type(4)));
typedef float  f32x16 __attribute__((ext_vector_type(16)));
typedef short  bf16x8 __attribute__((ext_vector_type(8)));
union FragU { bf16x8 v; uint32_t u[4]; uint16_t h[8]; };

static __device__ __forceinline__ uint32_t rne_bits(float f) {
  uint32_t u = __float_as_uint(f);
  return u + 0x7fffu + ((u >> 16) & 1u);   // high16 = rne bf16
}
static __device__ __forceinline__ float fsigm(float z) {
  return __builtin_amdgcn_rcpf(1.0f + __builtin_amdgcn_exp2f(z * -1.44269504089f));
}
// dst.lo = bf16_rne(a), dst.hi = bf16_rne(b)
static __device__ __forceinline__ uint32_t cvt_pk_bf16(float a, float b) {
  uint32_t r;
  asm("v_cvt_pk_bf16_f32 %0, %1, %2" : "=v"(r) : "v"(a), "v"(b));
  return r;
}

// ---- prep: 6 fragment-order (32x32x16 A-layout) split-bf16 W images ----
// img 0..2: forward A = W^T of w2,w3,w4 (m=out, k=in)
// img 3..5: backward A = W natural of w4,w3,w2 (m=in, k=out)
extern "C" __global__ void ebm_prep_kernel(const float* __restrict__ w2,
                                           const float* __restrict__ w3,
                                           const float* __restrict__ w4,
                                           uint16_t* __restrict__ ws) {
  int img = blockIdx.x;
  bool bwd = img >= 3;
  int li = bwd ? 5 - img : img;
  const float* w = (li == 0) ? w2 : (li == 1) ? w3 : w4;
  uint16_t* hiP = ws + (size_t)img * IMG_H;
  uint16_t* loP = hiP + PLANE_H;
  for (int e = threadIdx.x; e < 16384; e += blockDim.x) {
    int i = e >> 7, o = e & 127;            // w[i][o]
    int m = bwd ? i : o;
    int k = bwd ? o : i;
    int slot = ((m >> 5) * 8 + (k >> 4)) * 64 + (m & 31) + 32 * ((k >> 3) & 1);
    int off = slot * 8 + (k & 7);
    float v = w[e];
    uint32_t tb = rne_bits(v);
    float lo = v - __uint_as_float(tb & 0xffff0000u);
    hiP[off] = (uint16_t)(tb >> 16);
    loP[off] = (uint16_t)(rne_bits(lo) >> 16);
  }
}

extern "C" __global__ void __launch_bounds__(256, 3)
ebm_mcmc_kernel(const float* __restrict__ x0, const float* __restrict__ w1,
                const float* __restrict__ b1, const float* __restrict__ b2,
                const float* __restrict__ b3, const float* __restrict__ b4,
                const float* __restrict__ w5, const float* __restrict__ noise,
                const uint16_t* __restrict__ wsW, float* __restrict__ out)
{
  extern __shared__ char smem[];
  uint16_t* ACT0  = (uint16_t*)(smem + OFF_ACT0);   // ACT frag image, lo at +BPLANE_H
  uint16_t* ACT1  = (uint16_t*)(smem + OFF_ACT1);
  float*    GPf   = (float*)(smem + OFF_GP);        // [wr][32 samples][2]
  f32x4*    W1C   = (f32x4*)(smem + OFF_W1C);       // (w1[0][n], w1[1][n], b1[n], 0)
  float*    B2s   = (float*)(smem + OFF_B2);
  float*    B3s   = (float*)(smem + OFF_B3);
  float*    B4s   = (float*)(smem + OFF_B4);
  float*    W5s   = (float*)(smem + OFF_W5);
  float*    XB    = (float*)(smem + OFF_XB);        // x state fp32 [32][2]

  const int t   = threadIdx.x;
  const int blk = blockIdx.x;

  if (t < 128) {
    f32x4 v; v.x = w1[t]; v.y = w1[128 + t]; v.z = b1[t]; v.w = 0.0f;
    W1C[t] = v;
    B2s[t] = b2[t]; B3s[t] = b3[t]; B4s[t] = b4[t]; W5s[t] = w5[t];
  }
  if (t < 64) XB[t] = x0[(size_t)blk * 64 + t];

  const int lane = t & 63;
  const int wave = t >> 6;
  const int c32 = lane & 31;      // sample within 32-tile / A-row m
  const int h   = lane >> 5;      // lane half (k-half of frags; row offset 4h in C)
  const int wr  = wave;           // hidden rows 32*wr..+31

  size_t nbase = (size_t)blk * 64 + (t & 63);
  float nz = (t < 64) ? noise[nbase] : 0.0f;

  __syncthreads();

  f32x16 acc;                     // one 32x32 C tile per wave
  float D1[16], D2[16], D3[16];   // silu' fp32

  // A-frags stream straight from L2 (384 KB image set, L2-resident):
  // frag offset ((wr*8+ks)*64+lane)*8 halves, lo plane at +PLANE_H
  auto gemm = [&](int img, const uint16_t* AB) {
    const uint16_t* ab = wsW + (size_t)img * IMG_H + (size_t)(wr * 4096 + lane * 8);
    acc = (f32x16)0.0f;
#pragma unroll
    for (int ks = 0; ks < 8; ++ks) {
      FragU Ah, Al;
      Ah.v = *(const bf16x8*)(ab + ks * 512);
      Al.v = *(const bf16x8*)(ab + ks * 512 + PLANE_H);
      const uint16_t* bp = AB + (ks * 64 + lane) * 8;
      FragU Bh, Bl;
      Bh.v = *(const bf16x8*)bp;
      Bl.v = *(const bf16x8*)(bp + BPLANE_H);
      acc = __builtin_amdgcn_mfma_f32_32x32x16_bf16(Ah.v, Bh.v, acc, 0, 0, 0);
      acc = __builtin_amdgcn_mfma_f32_32x32x16_bf16(Ah.v, Bl.v, acc, 0, 0, 0);
      acc = __builtin_amdgcn_mfma_f32_32x32x16_bf16(Al.v, Bh.v, acc, 0, 0, 0);
    }
  };

  // C element (tt, rr) -> B-frag image: k = 32wr+8tt+4h+rr, n = c32
  auto storeAct = [&](uint16_t* AB, int tt, f32x4 v) {
    uint32_t h01 = cvt_pk_bf16(v[0], v[1]);
    uint32_t h23 = cvt_pk_bf16(v[2], v[3]);
    float r0 = v[0] - __uint_as_float(h01 << 16);
    float r1 = v[1] - __uint_as_float(h01 & 0xffff0000u);
    float r2 = v[2] - __uint_as_float(h23 << 16);
    float r3 = v[3] - __uint_as_float(h23 & 0xffff0000u);
    int slot = (2 * wr + (tt >> 1)) * 64 + c32 + 32 * (tt & 1);
    uint16_t* p = AB + slot * 8 + 4 * h;
    *(uint2*)p = make_uint2(h01, h23);
    *(uint2*)(p + BPLANE_H) = make_uint2(cvt_pk_bf16(r0, r1), cvt_pk_bf16(r2, r3));
  };

  auto ep_fwd = [&](const float* Bs, float* D, uint16_t* AB) {
#pragma unroll
    for (int tt = 0; tt < 4; ++tt) {
      f32x4 bv = *(const f32x4*)(Bs + 32 * wr + 8 * tt + 4 * h);
      f32x4 hv;
#pragma unroll
      for (int rr = 0; rr < 4; ++rr) {
        float z = acc[4 * tt + rr] + bv[rr];
        float s = fsigm(z);
        float hh = z * s;
        D[4 * tt + rr] = s * (1.0f + z - hh);
        hv[rr] = hh;
      }
      storeAct(AB, tt, hv);
    }
  };

  auto ep_v4 = [&](uint16_t* AB) {
#pragma unroll
    for (int tt = 0; tt < 4; ++tt) {
      f32x4 bv = *(const f32x4*)(B4s + 32 * wr + 8 * tt + 4 * h);
      f32x4 wv = *(const f32x4*)(W5s + 32 * wr + 8 * tt + 4 * h);
      f32x4 vv;
#pragma unroll
      for (int rr = 0; rr < 4; ++rr) {
        float z = acc[4 * tt + rr] + bv[rr];
        float s = fsigm(z);
        vv[rr] = wv[rr] * (s * (1.0f + z - z * s));
      }
      storeAct(AB, tt, vv);
    }
  };

  auto ep_bwd = [&](float* D, uint16_t* AB) {
#pragma unroll
    for (int tt = 0; tt < 4; ++tt) {
      f32x4 vv;
#pragma unroll
      for (int rr = 0; rr < 4; ++rr)
        vv[rr] = acc[4 * tt + rr] * D[4 * tt + rr];
      storeAct(AB, tt, vv);
    }
  };

  // u1 epilogue: v1 = acc .* D1 ; in-register contraction against w1 -> GP
  auto ep_bwd1 = [&]() {
    float gx = 0.f, gy = 0.f;
#pragma unroll
    for (int tt = 0; tt < 4; ++tt) {
      const f32x4* wp = W1C + 32 * wr + 8 * tt + 4 * h;
#pragma unroll
      for (int rr = 0; rr < 4; ++rr) {
        f32x4 w = wp[rr];
        float v = acc[4 * tt + rr] * D1[4 * tt + rr];
        gx = fmaf(v, w.x, gx);
        gy = fmaf(v, w.y, gy);
      }
    }
    gx += __shfl_xor(gx, 32);
    gy += __shfl_xor(gy, 32);
    if (h == 0) {
      *(float2*)(GPf + (wr * 32 + c32) * 2) = make_float2(gx, gy);
    }
  };

  auto l1_phase = [&](uint16_t* AB) {
    float2 xv = *(const float2*)(XB + 2 * c32);
#pragma unroll
    for (int tt = 0; tt < 4; ++tt) {
      const f32x4* wp = W1C + 32 * wr + 8 * tt + 4 * h;
      f32x4 hv;
#pragma unroll
      for (int rr = 0; rr < 4; ++rr) {
        f32x4 w = wp[rr];
        float z = fmaf(xv.x, w.x, fmaf(xv.y, w.y, w.z));
        float s = fsigm(z);
        float hh = z * s;
        D1[4 * tt + rr] = s * (1.0f + z - hh);
        hv[rr] = hh;
      }
      storeAct(AB, tt, hv);
    }
  };

  auto g_finish = [&](int step) {
    if (t < 64) {
      float g = GPf[t] + GPf[64 + t] + GPf[128 + t] + GPf[192 + t];
      g = fminf(fmaxf(g, -0.03f), 0.03f);
      float epsv = 10.0f * (1.0f - (float)step / 60.0f);
      float xn = XB[t] + sqrtf(2.0f * epsv) * nz * 0.005f + epsv * g;
      xn = fminf(fmaxf(xn, -2.43f), 3.05f);
      XB[t] = xn;
      if (step == NSTEP - 1) {
        out[(size_t)blk * 64 + t] = xn;
      } else {
        nz = noise[(size_t)(step + 1) * NTOT * 2 + nbase];
      }
    }
  };

  // Double-buffered ACT: gemm reads one image while the fused epilogue
  // writes the other -> ONE barrier per phase (8/step instead of 14).
#pragma unroll 1
  for (int step = 0; step < NSTEP; ++step) {
    l1_phase(ACT0);                 __syncthreads();
    gemm(0, ACT0); ep_fwd(B2s, D2, ACT1); __syncthreads();   // z2 (A = W2^T)
    gemm(1, ACT1); ep_fwd(B3s, D3, ACT0); __syncthreads();   // z3
    gemm(2, ACT0); ep_v4(ACT1);           __syncthreads();   // z4
    gemm(3, ACT1); ep_bwd(D3, ACT0);      __syncthreads();   // u3 (A = W4 nat)
    gemm(4, ACT0); ep_bwd(D2, ACT1);      __syncthreads();   // u2
    gemm(5, ACT1); ep_bwd1();             __syncthreads();   // u1 -> g partials
    g_finish(step);                 __syncthreads();
  }
}

extern "C" void kernel_launch(void* const* d_in, const int* in_sizes, int n_in,
                              void* d_out, int out_size, void* d_ws, size_t ws_size,
                              hipStream_t stream) {
  // inputs: x0,w1,b1,w2,b2,w3,b3,w4,b4,w5,b5,noise
  (void)in_sizes; (void)n_in; (void)out_size; (void)ws_size;
  hipFuncSetAttribute((const void*)ebm_mcmc_kernel,
                      hipFuncAttributeMaxDynamicSharedMemorySize, LDS_TOTAL);
  ebm_prep_kernel<<<6, 256, 0, stream>>>(
      (const float*)d_in[3], (const float*)d_in[5], (const float*)d_in[7],
      (uint16_t*)d_ws);
  ebm_mcmc_kernel<<<NBLK, 256, LDS_TOTAL, stream>>>(
      (const float*)d_in[0], (const float*)d_in[1], (const float*)d_in[2],
      (const float*)d_in[4], (const float*)d_in[6], (const float*)d_in[8],
      (const float*)d_in[9], (const float*)d_in[11], (const uint16_t*)d_ws,
      (float*)d_out);
}

// Round 5
// 5861.980 us; speedup vs baseline: 1.6468x; 1.6468x over previous
//
#include <hip/hip_runtime.h>
#include <stdint.h>

#define NTOT    131072
#define NSTEP   60
#define SBLK    32             // samples per block: 4 waves, 1 wave/SIMD quantum
#define NBLK    (NTOT / SBLK)  // 4096 blocks
#define PLANE_H 16384          // halves per A-image plane (128x128 frag order)
#define IMG_H   32768          // halves per A image (hi + lo plane)
#define BPLANE_H 4096          // halves per ACT plane (128k x 32n frag order)
#define ACT_H   8192           // halves per ACT image (hi + lo)

// LDS: double-buffered ACT (2 x 16 KB) kills the gemm<->epilogue barrier.
// 38.1 KB/block -> up to 4 blocks/CU if regs allow.
#define OFF_ACT0 0             // 16384 B
#define OFF_ACT1 16384         // 16384 B
#define OFF_GP   32768         // 4*32*2*4 = 1024 B
#define OFF_W1C  33792         // 2048 B
#define OFF_B2   35840         // 512 B
#define OFF_B3   36352
#define OFF_B4   36864
#define OFF_W5   37376
#define OFF_XB   37888         // 32*2*4 = 256 B
#define LDS_TOTAL 38144

typedef float  f32x4  __attribute__((ext_vector_type(4)));
typedef float  f32x16 __attribute__((ext_vector_type(16)));
typedef short  bf16x8 __attribute__((ext_vector_type(8)));
union FragU { bf16x8 v; uint32_t u[4]; uint16_t h[8]; };

static __device__ __forceinline__ uint32_t rne_bits(float f) {
  uint32_t u = __float_as_uint(f);
  return u + 0x7fffu + ((u >> 16) & 1u);   // high16 = rne bf16
}
static __device__ __forceinline__ float fsigm(float z) {
  return __builtin_amdgcn_rcpf(1.0f + __builtin_amdgcn_exp2f(z * -1.44269504089f));
}
// dst.lo = bf16_rne(a), dst.hi = bf16_rne(b)
static __device__ __forceinline__ uint32_t cvt_pk_bf16(float a, float b) {
  uint32_t r;
  asm("v_cvt_pk_bf16_f32 %0, %1, %2" : "=v"(r) : "v"(a), "v"(b));
  return r;
}

// ---- prep: 6 fragment-order (32x32x16 A-layout) split-bf16 W images ----
// img 0..2: forward A = W^T of w2,w3,w4 (m=out, k=in)
// img 3..5: backward A = W natural of w4,w3,w2 (m=in, k=out)
extern "C" __global__ void ebm_prep_kernel(const float* __restrict__ w2,
                                           const float* __restrict__ w3,
                                           const float* __restrict__ w4,
                                           uint16_t* __restrict__ ws) {
  int img = blockIdx.x;
  bool bwd = img >= 3;
  int li = bwd ? 5 - img : img;
  const float* w = (li == 0) ? w2 : (li == 1) ? w3 : w4;
  uint16_t* hiP = ws + (size_t)img * IMG_H;
  uint16_t* loP = hiP + PLANE_H;
  for (int e = threadIdx.x; e < 16384; e += blockDim.x) {
    int i = e >> 7, o = e & 127;            // w[i][o]
    int m = bwd ? i : o;
    int k = bwd ? o : i;
    int slot = ((m >> 5) * 8 + (k >> 4)) * 64 + (m & 31) + 32 * ((k >> 3) & 1);
    int off = slot * 8 + (k & 7);
    float v = w[e];
    uint32_t tb = rne_bits(v);
    float lo = v - __uint_as_float(tb & 0xffff0000u);
    hiP[off] = (uint16_t)(tb >> 16);
    loP[off] = (uint16_t)(rne_bits(lo) >> 16);
  }
}

extern "C" __global__ void __launch_bounds__(256, 2)
ebm_mcmc_kernel(const float* __restrict__ x0, const float* __restrict__ w1,
                const float* __restrict__ b1, const float* __restrict__ b2,
                const float* __restrict__ b3, const float* __restrict__ b4,
                const float* __restrict__ w5, const float* __restrict__ noise,
                const uint16_t* __restrict__ wsW, float* __restrict__ out)
{
  extern __shared__ char smem[];
  uint16_t* ACT0  = (uint16_t*)(smem + OFF_ACT0);   // ACT frag image, lo at +BPLANE_H
  uint16_t* ACT1  = (uint16_t*)(smem + OFF_ACT1);
  float*    GPf   = (float*)(smem + OFF_GP);        // [wr][32 samples][2]
  f32x4*    W1C   = (f32x4*)(smem + OFF_W1C);       // (w1[0][n], w1[1][n], b1[n], 0)
  float*    B2s   = (float*)(smem + OFF_B2);
  float*    B3s   = (float*)(smem + OFF_B3);
  float*    B4s   = (float*)(smem + OFF_B4);
  float*    W5s   = (float*)(smem + OFF_W5);
  float*    XB    = (float*)(smem + OFF_XB);        // x state fp32 [32][2]

  const int t   = threadIdx.x;
  const int blk = blockIdx.x;

  if (t < 128) {
    f32x4 v; v.x = w1[t]; v.y = w1[128 + t]; v.z = b1[t]; v.w = 0.0f;
    W1C[t] = v;
    B2s[t] = b2[t]; B3s[t] = b3[t]; B4s[t] = b4[t]; W5s[t] = w5[t];
  }
  if (t < 64) XB[t] = x0[(size_t)blk * 64 + t];

  const int lane = t & 63;
  const int wave = t >> 6;
  const int c32 = lane & 31;      // sample within 32-tile / A-row m
  const int h   = lane >> 5;      // lane half (k-half of frags; row offset 4h in C)
  const int wr  = wave;           // hidden rows 32*wr..+31

  size_t nbase = (size_t)blk * 64 + (t & 63);
  float nz = (t < 64) ? noise[nbase] : 0.0f;

  __syncthreads();

  f32x16 acc;                     // one 32x32 C tile per wave
  float D1[16], D2[16], D3[16];   // silu' fp32

  // A-frags stream straight from L2 (384 KB image set, L2-resident):
  // frag offset ((wr*8+ks)*64+lane)*8 halves, lo plane at +PLANE_H
  auto gemm = [&](int img, const uint16_t* AB) {
    const uint16_t* ab = wsW + (size_t)img * IMG_H + (size_t)(wr * 4096 + lane * 8);
    acc = (f32x16)0.0f;
#pragma unroll
    for (int ks = 0; ks < 8; ++ks) {
      FragU Ah, Al;
      Ah.v = *(const bf16x8*)(ab + ks * 512);
      Al.v = *(const bf16x8*)(ab + ks * 512 + PLANE_H);
      const uint16_t* bp = AB + (ks * 64 + lane) * 8;
      FragU Bh, Bl;
      Bh.v = *(const bf16x8*)bp;
      Bl.v = *(const bf16x8*)(bp + BPLANE_H);
      acc = __builtin_amdgcn_mfma_f32_32x32x16_bf16(Ah.v, Bh.v, acc, 0, 0, 0);
      acc = __builtin_amdgcn_mfma_f32_32x32x16_bf16(Ah.v, Bl.v, acc, 0, 0, 0);
      acc = __builtin_amdgcn_mfma_f32_32x32x16_bf16(Al.v, Bh.v, acc, 0, 0, 0);
    }
  };

  // C element (tt, rr) -> B-frag image: k = 32wr+8tt+4h+rr, n = c32
  auto storeAct = [&](uint16_t* AB, int tt, f32x4 v) {
    uint32_t h01 = cvt_pk_bf16(v[0], v[1]);
    uint32_t h23 = cvt_pk_bf16(v[2], v[3]);
    float r0 = v[0] - __uint_as_float(h01 << 16);
    float r1 = v[1] - __uint_as_float(h01 & 0xffff0000u);
    float r2 = v[2] - __uint_as_float(h23 << 16);
    float r3 = v[3] - __uint_as_float(h23 & 0xffff0000u);
    int slot = (2 * wr + (tt >> 1)) * 64 + c32 + 32 * (tt & 1);
    uint16_t* p = AB + slot * 8 + 4 * h;
    *(uint2*)p = make_uint2(h01, h23);
    *(uint2*)(p + BPLANE_H) = make_uint2(cvt_pk_bf16(r0, r1), cvt_pk_bf16(r2, r3));
  };

  auto ep_fwd = [&](const float* Bs, float* D, uint16_t* AB) {
#pragma unroll
    for (int tt = 0; tt < 4; ++tt) {
      f32x4 bv = *(const f32x4*)(Bs + 32 * wr + 8 * tt + 4 * h);
      f32x4 hv;
#pragma unroll
      for (int rr = 0; rr < 4; ++rr) {
        float z = acc[4 * tt + rr] + bv[rr];
        float s = fsigm(z);
        float hh = z * s;
        D[4 * tt + rr] = s * (1.0f + z - hh);
        hv[rr] = hh;
      }
      storeAct(AB, tt, hv);
    }
  };

  auto ep_v4 = [&](uint16_t* AB) {
#pragma unroll
    for (int tt = 0; tt < 4; ++tt) {
      f32x4 bv = *(const f32x4*)(B4s + 32 * wr + 8 * tt + 4 * h);
      f32x4 wv = *(const f32x4*)(W5s + 32 * wr + 8 * tt + 4 * h);
      f32x4 vv;
#pragma unroll
      for (int rr = 0; rr < 4; ++rr) {
        float z = acc[4 * tt + rr] + bv[rr];
        float s = fsigm(z);
        vv[rr] = wv[rr] * (s * (1.0f + z - z * s));
      }
      storeAct(AB, tt, vv);
    }
  };

  auto ep_bwd = [&](float* D, uint16_t* AB) {
#pragma unroll
    for (int tt = 0; tt < 4; ++tt) {
      f32x4 vv;
#pragma unroll
      for (int rr = 0; rr < 4; ++rr)
        vv[rr] = acc[4 * tt + rr] * D[4 * tt + rr];
      storeAct(AB, tt, vv);
    }
  };

  // u1 epilogue: v1 = acc .* D1 ; in-register contraction against w1 -> GP
  auto ep_bwd1 = [&]() {
    float gx = 0.f, gy = 0.f;
#pragma unroll
    for (int tt = 0; tt < 4; ++tt) {
      const f32x4* wp = W1C + 32 * wr + 8 * tt + 4 * h;
#pragma unroll
      for (int rr = 0; rr < 4; ++rr) {
        f32x4 w = wp[rr];
        float v = acc[4 * tt + rr] * D1[4 * tt + rr];
        gx = fmaf(v, w.x, gx);
        gy = fmaf(v, w.y, gy);
      }
    }
    gx += __shfl_xor(gx, 32);
    gy += __shfl_xor(gy, 32);
    if (h == 0) {
      *(float2*)(GPf + (wr * 32 + c32) * 2) = make_float2(gx, gy);
    }
  };

  auto l1_phase = [&](uint16_t* AB) {
    float2 xv = *(const float2*)(XB + 2 * c32);
#pragma unroll
    for (int tt = 0; tt < 4; ++tt) {
      const f32x4* wp = W1C + 32 * wr + 8 * tt + 4 * h;
      f32x4 hv;
#pragma unroll
      for (int rr = 0; rr < 4; ++rr) {
        f32x4 w = wp[rr];
        float z = fmaf(xv.x, w.x, fmaf(xv.y, w.y, w.z));
        float s = fsigm(z);
        float hh = z * s;
        D1[4 * tt + rr] = s * (1.0f + z - hh);
        hv[rr] = hh;
      }
      storeAct(AB, tt, hv);
    }
  };

  auto g_finish = [&](int step) {
    if (t < 64) {
      float g = GPf[t] + GPf[64 + t] + GPf[128 + t] + GPf[192 + t];
      g = fminf(fmaxf(g, -0.03f), 0.03f);
      float epsv = 10.0f * (1.0f - (float)step / 60.0f);
      float xn = XB[t] + sqrtf(2.0f * epsv) * nz * 0.005f + epsv * g;
      xn = fminf(fmaxf(xn, -2.43f), 3.05f);
      XB[t] = xn;
      if (step == NSTEP - 1) {
        out[(size_t)blk * 64 + t] = xn;
      } else {
        nz = noise[(size_t)(step + 1) * NTOT * 2 + nbase];
      }
    }
  };

  // Double-buffered ACT: gemm reads one image while the fused epilogue
  // writes the other -> ONE barrier per phase (8/step instead of 14).
#pragma unroll 1
  for (int step = 0; step < NSTEP; ++step) {
    l1_phase(ACT0);                 __syncthreads();
    gemm(0, ACT0); ep_fwd(B2s, D2, ACT1); __syncthreads();   // z2 (A = W2^T)
    gemm(1, ACT1); ep_fwd(B3s, D3, ACT0); __syncthreads();   // z3
    gemm(2, ACT0); ep_v4(ACT1);           __syncthreads();   // z4
    gemm(3, ACT1); ep_bwd(D3, ACT0);      __syncthreads();   // u3 (A = W4 nat)
    gemm(4, ACT0); ep_bwd(D2, ACT1);      __syncthreads();   // u2
    gemm(5, ACT1); ep_bwd1();             __syncthreads();   // u1 -> g partials
    g_finish(step);                 __syncthreads();
  }
}

extern "C" void kernel_launch(void* const* d_in, const int* in_sizes, int n_in,
                              void* d_out, int out_size, void* d_ws, size_t ws_size,
                              hipStream_t stream) {
  // inputs: x0,w1,b1,w2,b2,w3,b3,w4,b4,w5,b5,noise
  (void)in_sizes; (void)n_in; (void)out_size; (void)ws_size;
  hipFuncSetAttribute((const void*)ebm_mcmc_kernel,
                      hipFuncAttributeMaxDynamicSharedMemorySize, LDS_TOTAL);
  ebm_prep_kernel<<<6, 256, 0, stream>>>(
      (const float*)d_in[3], (const float*)d_in[5], (const float*)d_in[7],
      (uint16_t*)d_ws);
  ebm_mcmc_kernel<<<NBLK, 256, LDS_TOTAL, stream>>>(
      (const float*)d_in[0], (const float*)d_in[1], (const float*)d_in[2],
      (const float*)d_in[4], (const float*)d_in[6], (const float*)d_in[8],
      (const float*)d_in[9], (const float*)d_in[11], (const uint16_t*)d_ws,
      (float*)d_out);
}